// Round 5
// baseline (572.533 us; speedup 1.0000x reference)
//
#include <hip/hip_runtime.h>
#include <math.h>

namespace {
constexpr int S = 7;
constexpr int B = 2;
constexpr int C = 20;
constexpr int PF = B * 5 + C;   // 30 floats per cell (predictions)
constexpr int TF = 5 + C;       // 25 floats per cell (targets)
constexpr float EPS = 1e-6f;
constexpr float LAMBDA_COORD = 5.0f;
constexpr float LAMBDA_NOOBJ = 0.5f;

// stream kernel split: pred blocks / tgt blocks (balanced by bytes; both give
// exact whole iteration counts for the bench shape)
constexpr int PBLK = 1120;
constexpr int TBLK = 980;
constexpr int OBLK = 256;        // obj-gather kernel blocks

// workspace layout (floats): [0]=counter, part1 @ 8 (PBLK), part2 @ 2048
// (OBLK*4), obj list (uint) @ 4096
constexpr int WS_PART1 = 8;
constexpr int WS_PART2 = 2048;
constexpr int WS_LIST  = 4096;
}

// ---------------- pure-stream pass: noobj conf^2 sum + obj-cell compaction --
__global__ __launch_bounds__(256) void k_stream(const float4* __restrict__ p4,
                                                const float4* __restrict__ t4,
                                                int n_cells,
                                                float* __restrict__ part1,
                                                unsigned* __restrict__ list,
                                                unsigned* __restrict__ counter)
{
    const int bid = blockIdx.x;
    const int tid = threadIdx.x;

    if (bid < PBLK) {
        // ---- pred stream: acc += q^2 where float-pos % 30 in {4, 9} ----
        const int NT = PBLK * 256;
        const int np = n_cells * PF;
        const int np4 = np >> 2;
        int i = bid * 256 + tid;
        int r = (4 * i) % 30;               // pos of q.x
        const int step = (4 * NT) % 30;
        float acc = 0.f;
        for (; i < np4; i += NT) {
            const float4 q = p4[i];
            acc += ((r == 4) | (r == 9)) ? q.x * q.x : 0.f;
            acc += ((r == 3) | (r == 8)) ? q.y * q.y : 0.f;
            acc += ((r == 2) | (r == 7)) ? q.z * q.z : 0.f;
            acc += ((r == 1) | (r == 6)) ? q.w * q.w : 0.f;
            r += step; if (r >= 30) r -= 30;
        }
        // scalar tail (np % 4 != 0 never happens for even n_cells)
        if (bid == 0 && tid == 0) {
            const float* pf = (const float*)p4;
            for (int f = np4 * 4; f < np; ++f) {
                const int pos = f % 30;
                if (pos == 4 || pos == 9) acc += pf[f] * pf[f];
            }
        }
        // reduce acc -> part1[bid]
        #pragma unroll
        for (int off = 32; off >= 1; off >>= 1) acc += __shfl_down(acc, off, 64);
        __shared__ float red[4];
        if ((tid & 63) == 0) red[tid >> 6] = acc;
        __syncthreads();
        if (tid == 0) part1[bid] = red[0] + red[1] + red[2] + red[3];
    } else {
        // ---- tgt stream: find floats with pos % 25 == 4 and value > 0 ----
        const int NT = TBLK * 256;
        const int nt = n_cells * TF;
        const int nt4 = nt >> 2;
        int i = (bid - PBLK) * 256 + tid;
        int r = (4 * i) % 25;               // pos of q.x
        const int step = (4 * NT) % 25;
        const int lane = tid & 63;
        for (; i < nt4; i += NT) {
            const float4 q = t4[i];
            bool hit = false;
            int e = 0;
            if (r >= 1 && r <= 4) {         // element (4-r) has pos % 25 == 4
                e = 4 - r;
                const float val = (e == 0) ? q.x : (e == 1) ? q.y
                                 : (e == 2) ? q.z : q.w;
                hit = val > 0.f;
            }
            const unsigned long long mask = __ballot(hit);
            if (mask) {
                const int leader = __ffsll((long long)mask) - 1;
                unsigned base = 0;
                if (lane == leader)
                    base = atomicAdd(counter, (unsigned)__popcll(mask));
                base = (unsigned)__shfl((int)base, leader, 64);
                if (hit) {
                    const int pos = __popcll(mask & ((1ull << lane) - 1ull));
                    const unsigned f = (unsigned)(4 * i + e);
                    list[base + pos] = (f - 4u) / 25u;   // cell index
                }
            }
            r += step; if (r >= 25) r -= 25;
        }
        // scalar tail
        if (bid == PBLK && tid == 0) {
            const float* tf = (const float*)t4;
            for (int f = nt4 * 4; f < nt; ++f) {
                if (f % 25 == 4 && tf[f] > 0.f) {
                    const unsigned b = atomicAdd(counter, 1u);
                    list[b] = (unsigned)(f - 4) / 25u;
                }
            }
        }
    }
}

// ---------------- obj pass: gather ~6% cells, full loss terms ---------------
__global__ __launch_bounds__(256) void k_obj(const float* __restrict__ pred,
                                             const float* __restrict__ tgt,
                                             const unsigned* __restrict__ list,
                                             const unsigned* __restrict__ counter,
                                             float* __restrict__ part2)
{
    const unsigned count = *counter;
    float v0 = 0.f, v1 = 0.f, v2 = 0.f, v3 = 0.f;   // v2 = -rconf^2 correction

    for (unsigned idx = blockIdx.x * 256 + threadIdx.x; idx < count;
         idx += OBLK * 256) {
        const unsigned cell = list[idx];
        const float* p = pred + (size_t)cell * PF;
        const float* t = tgt + (size_t)cell * TF;

        const int j = (int)(cell % S);
        const int i = (int)((cell / S) % S);
        const float invS = 1.0f / (float)S;

        const float2 p01 = *(const float2*)(p + 0);
        const float2 p23 = *(const float2*)(p + 2);
        const float2 p45 = *(const float2*)(p + 4);
        const float2 p67 = *(const float2*)(p + 6);
        const float2 p89 = *(const float2*)(p + 8);
        const float gx = t[0], gy = t[1], gw = t[2], gh = t[3];

        const float gcx = ((float)j + gx) * invS;
        const float gcy = ((float)i + gy) * invS;
        const float gx1 = gcx - gw * 0.5f, gy1 = gcy - gh * 0.5f;
        const float gx2 = gcx + gw * 0.5f, gy2 = gcy + gh * 0.5f;
        const float garea = (gx2 - gx1) * (gy2 - gy1);

        const float bx[B]  = {p01.x, p45.y};
        const float by[B]  = {p01.y, p67.x};
        const float bw_[B] = {p23.x, p67.y};
        const float bh[B]  = {p23.y, p89.x};
        const float cf[B]  = {p45.x, p89.y};
        float iou[B];
        #pragma unroll
        for (int b = 0; b < B; ++b) {
            const float cx = ((float)j + bx[b]) * invS;
            const float cy = ((float)i + by[b]) * invS;
            const float x1 = cx - bw_[b] * 0.5f, y1 = cy - bh[b] * 0.5f;
            const float x2 = cx + bw_[b] * 0.5f, y2 = cy + bh[b] * 0.5f;
            const float ix1 = fmaxf(x1, gx1), iy1 = fmaxf(y1, gy1);
            const float ix2 = fminf(x2, gx2), iy2 = fminf(y2, gy2);
            const float inter = fmaxf(ix2 - ix1, 0.f) * fmaxf(iy2 - iy1, 0.f);
            const float parea = (x2 - x1) * (y2 - y1);
            iou[b] = inter / (parea + garea - inter + EPS);
        }
        const int best = (iou[1] > iou[0]) ? 1 : 0;
        const float rconf = cf[best], riou = iou[best];

        const float dx = bx[best] - gx, dy = by[best] - gy;
        const float swd = sqrtf(bw_[best] + EPS) - sqrtf(gw + EPS);
        const float shd = sqrtf(bh[best] + EPS) - sqrtf(gh + EPS);
        v0 += dx * dx + dy * dy + swd * swd + shd * shd;
        const float dc = rconf - riou;
        v1 += dc * dc;
        v2 -= rconf * rconf;

        float se = 0.f, dot = 0.f, sg = 0.f;
        #pragma unroll
        for (int c = 0; c < C; c += 2) {
            const float2 lc = *(const float2*)(p + 10 + c);
            const float g0 = t[5 + c], g1 = t[6 + c];
            se  += __expf(lc.x) + __expf(lc.y);
            dot += g0 * lc.x + g1 * lc.y;
            sg  += g0 + g1;
        }
        v3 += __logf(se) * sg - dot;
    }

    float v[4] = {v0, v1, v2, v3};
    #pragma unroll
    for (int off = 32; off >= 1; off >>= 1) {
        v[0] += __shfl_down(v[0], off, 64);
        v[1] += __shfl_down(v[1], off, 64);
        v[2] += __shfl_down(v[2], off, 64);
        v[3] += __shfl_down(v[3], off, 64);
    }
    __shared__ float red[16];
    const int lane = threadIdx.x & 63;
    const int wave = threadIdx.x >> 6;
    if (lane == 0) {
        red[wave * 4 + 0] = v[0];
        red[wave * 4 + 1] = v[1];
        red[wave * 4 + 2] = v[2];
        red[wave * 4 + 3] = v[3];
    }
    __syncthreads();
    if (threadIdx.x < 4)
        part2[blockIdx.x * 4 + threadIdx.x] =
            red[threadIdx.x] + red[4 + threadIdx.x] +
            red[8 + threadIdx.x] + red[12 + threadIdx.x];
}

__global__ void k_zero(unsigned* counter) { *counter = 0u; }

// ---------------- final reduce -------------------------------------------
__global__ __launch_bounds__(256) void k_fin2(const float* __restrict__ part1,
                                              const float* __restrict__ part2,
                                              float* __restrict__ out, float n)
{
    const int tid = threadIdx.x;
    float a0 = 0.f, a1 = 0.f, a2 = 0.f, a3 = 0.f;
    for (int r = tid; r < PBLK; r += 256) a2 += part1[r];      // noobj base
    for (int r = tid; r < OBLK; r += 256) {
        const float4 q = *(const float4*)(part2 + r * 4);
        a0 += q.x; a1 += q.y; a2 += q.z; a3 += q.w;
    }
    float v[4] = {a0, a1, a2, a3};
    #pragma unroll
    for (int off = 32; off >= 1; off >>= 1) {
        v[0] += __shfl_down(v[0], off, 64);
        v[1] += __shfl_down(v[1], off, 64);
        v[2] += __shfl_down(v[2], off, 64);
        v[3] += __shfl_down(v[3], off, 64);
    }
    __shared__ float red[16];
    const int lane = tid & 63;
    const int wave = tid >> 6;
    if (lane == 0) {
        red[wave * 4 + 0] = v[0];
        red[wave * 4 + 1] = v[1];
        red[wave * 4 + 2] = v[2];
        red[wave * 4 + 3] = v[3];
    }
    __syncthreads();
    if (tid == 0) {
        const float coord  = red[0] + red[4] + red[8]  + red[12];
        const float cobj   = red[1] + red[5] + red[9]  + red[13];
        const float cnoobj = red[2] + red[6] + red[10] + red[14];
        const float ccls   = red[3] + red[7] + red[11] + red[15];
        const float inv = 1.0f / n;
        out[0] = coord * inv;
        out[1] = cobj * inv;
        out[2] = cnoobj * inv;
        out[3] = ccls * inv;
        out[4] = (LAMBDA_COORD * coord + cobj + LAMBDA_NOOBJ * cnoobj + ccls) * inv;
    }
}

// ---------------- fallback (round-1 staged kernel) if ws too small ----------
__global__ __launch_bounds__(256) void k_main_fb(const float* __restrict__ pred,
                                                 const float* __restrict__ tgt,
                                                 float* __restrict__ part,
                                                 int n_cells) {
    __shared__ float lp[256 * PF];
    __shared__ float lt[256 * TF];
    const int tid = threadIdx.x;
    const int block0 = blockIdx.x * 256;
    const int cells = min(256, n_cells - block0);
    const size_t pbase = (size_t)block0 * PF;
    const size_t tbase = (size_t)block0 * TF;
    for (int o = tid; o < cells * PF; o += 256) lp[o] = pred[pbase + o];
    for (int o = tid; o < cells * TF; o += 256) lt[o] = tgt[tbase + o];
    __syncthreads();

    float v0 = 0.f, v1 = 0.f, v2 = 0.f, v3 = 0.f;
    if (tid < cells) {
        const int cell = block0 + tid;
        const float* p = lp + tid * PF;
        const float* t = lt + tid * TF;
        const float c0 = p[4], c1 = p[9];
        v2 = c0 * c0 + c1 * c1;
        if (t[4] > 0.f) {
            const int j = cell % S;
            const int i = (cell / S) % S;
            const float invS = 1.0f / (float)S;
            const float gx = t[0], gy = t[1], gw = t[2], gh = t[3];
            const float gcx = ((float)j + gx) * invS;
            const float gcy = ((float)i + gy) * invS;
            const float gx1 = gcx - gw * 0.5f, gy1 = gcy - gh * 0.5f;
            const float gx2 = gcx + gw * 0.5f, gy2 = gcy + gh * 0.5f;
            const float garea = (gx2 - gx1) * (gy2 - gy1);
            const float bx[B]  = {p[0], p[5]};
            const float by[B]  = {p[1], p[6]};
            const float bw_[B] = {p[2], p[7]};
            const float bh[B]  = {p[3], p[8]};
            const float cf[B]  = {c0, c1};
            float iou[B];
            #pragma unroll
            for (int b = 0; b < B; ++b) {
                const float cx = ((float)j + bx[b]) * invS;
                const float cy = ((float)i + by[b]) * invS;
                const float x1 = cx - bw_[b] * 0.5f, y1 = cy - bh[b] * 0.5f;
                const float x2 = cx + bw_[b] * 0.5f, y2 = cy + bh[b] * 0.5f;
                const float ix1 = fmaxf(x1, gx1), iy1 = fmaxf(y1, gy1);
                const float ix2 = fminf(x2, gx2), iy2 = fminf(y2, gy2);
                const float inter = fmaxf(ix2 - ix1, 0.f) * fmaxf(iy2 - iy1, 0.f);
                const float parea = (x2 - x1) * (y2 - y1);
                iou[b] = inter / (parea + garea - inter + EPS);
            }
            const int best = (iou[1] > iou[0]) ? 1 : 0;
            const float rconf = cf[best], riou = iou[best];
            const float dx = bx[best] - gx, dy = by[best] - gy;
            const float swd = sqrtf(bw_[best] + EPS) - sqrtf(gw + EPS);
            const float shd = sqrtf(bh[best] + EPS) - sqrtf(gh + EPS);
            v0 = dx*dx + dy*dy + swd*swd + shd*shd;
            const float dc = rconf - riou;
            v1 = dc * dc;
            v2 -= rconf * rconf;
            float se = 0.f, dot = 0.f, sg = 0.f;
            #pragma unroll
            for (int c = 0; c < C; c += 2) {
                const float2 lc = *(const float2*)(p + 10 + c);
                const float g0 = t[5 + c], g1 = t[6 + c];
                se  += __expf(lc.x) + __expf(lc.y);
                dot += g0 * lc.x + g1 * lc.y;
                sg  += g0 + g1;
            }
            v3 = __logf(se) * sg - dot;
        }
    }
    float v[4] = {v0, v1, v2, v3};
    #pragma unroll
    for (int off = 32; off >= 1; off >>= 1) {
        v[0] += __shfl_down(v[0], off, 64);
        v[1] += __shfl_down(v[1], off, 64);
        v[2] += __shfl_down(v[2], off, 64);
        v[3] += __shfl_down(v[3], off, 64);
    }
    __shared__ float red[16];
    const int lane = tid & 63;
    const int wave = tid >> 6;
    if (lane == 0) {
        red[wave*4+0] = v[0]; red[wave*4+1] = v[1];
        red[wave*4+2] = v[2]; red[wave*4+3] = v[3];
    }
    __syncthreads();
    if (tid < 4)
        part[blockIdx.x * 4 + tid] =
            red[tid] + red[4+tid] + red[8+tid] + red[12+tid];
}

__global__ __launch_bounds__(256) void k_fin_fb(const float* __restrict__ part,
                                                float* __restrict__ out,
                                                int nblk, float n) {
    const int tid = threadIdx.x;
    float a0 = 0.f, a1 = 0.f, a2 = 0.f, a3 = 0.f;
    for (int r = tid; r < nblk; r += 256) {
        const float4 q = *(const float4*)(part + r * 4);
        a0 += q.x; a1 += q.y; a2 += q.z; a3 += q.w;
    }
    float v[4] = {a0, a1, a2, a3};
    #pragma unroll
    for (int off = 32; off >= 1; off >>= 1) {
        v[0] += __shfl_down(v[0], off, 64);
        v[1] += __shfl_down(v[1], off, 64);
        v[2] += __shfl_down(v[2], off, 64);
        v[3] += __shfl_down(v[3], off, 64);
    }
    __shared__ float red[16];
    const int lane = tid & 63;
    const int wave = tid >> 6;
    if (lane == 0) {
        red[wave*4+0] = v[0]; red[wave*4+1] = v[1];
        red[wave*4+2] = v[2]; red[wave*4+3] = v[3];
    }
    __syncthreads();
    if (tid == 0) {
        const float coord  = red[0] + red[4] + red[8]  + red[12];
        const float cobj   = red[1] + red[5] + red[9]  + red[13];
        const float cnoobj = red[2] + red[6] + red[10] + red[14];
        const float ccls   = red[3] + red[7] + red[11] + red[15];
        const float inv = 1.0f / n;
        out[0] = coord * inv;
        out[1] = cobj * inv;
        out[2] = cnoobj * inv;
        out[3] = ccls * inv;
        out[4] = (LAMBDA_COORD * coord + cobj + LAMBDA_NOOBJ * cnoobj + ccls) * inv;
    }
}

extern "C" void kernel_launch(void* const* d_in, const int* in_sizes, int n_in,
                              void* d_out, int out_size, void* d_ws, size_t ws_size,
                              hipStream_t stream) {
    const float* pred = (const float*)d_in[0];
    const float* tgt  = (const float*)d_in[1];
    float* out = (float*)d_out;
    float* wsf = (float*)d_ws;

    const int n_cells = in_sizes[0] / PF;          // 802816
    const float bs = (float)(n_cells / (S * S));   // 16384

    const size_t need = ((size_t)WS_LIST + (size_t)n_cells) * 4;
    if (ws_size >= need) {
        unsigned* counter = (unsigned*)d_ws;
        float* part1 = wsf + WS_PART1;
        float* part2 = wsf + WS_PART2;
        unsigned* list = (unsigned*)(wsf + WS_LIST);

        k_zero<<<1, 1, 0, stream>>>(counter);
        k_stream<<<PBLK + TBLK, 256, 0, stream>>>(
            (const float4*)pred, (const float4*)tgt, n_cells,
            part1, list, counter);
        k_obj<<<OBLK, 256, 0, stream>>>(pred, tgt, list, counter, part2);
        k_fin2<<<1, 256, 0, stream>>>(part1, part2, out, bs);
    } else {
        float* part = wsf;
        const int nblk = (n_cells + 255) / 256;
        k_main_fb<<<nblk, 256, 0, stream>>>(pred, tgt, part, n_cells);
        k_fin_fb<<<1, 256, 0, stream>>>(part, out, nblk, bs);
    }
}

// Round 6
// 211.594 us; speedup vs baseline: 2.7058x; 2.7058x over previous
//
#include <hip/hip_runtime.h>
#include <math.h>

namespace {
constexpr int S = 7;
constexpr int B = 2;
constexpr int C = 20;
constexpr int PF = B * 5 + C;   // 30 floats per cell (predictions)
constexpr int TF = 5 + C;       // 25 floats per cell (targets)
constexpr float EPS = 1e-6f;
constexpr float LAMBDA_COORD = 5.0f;
constexpr float LAMBDA_NOOBJ = 0.5f;

constexpr int PBLK2 = 2048;      // k_pred blocks (pure stream probe)
constexpr int TBLK2 = 1024;      // k_tscan blocks
constexpr int OBLK  = 256;       // k_obj blocks
constexpr int TCAP  = 1024;      // per-block LDS compaction capacity (bound ~820)

// workspace layout (floats): [0]=counter, part1 @ 64 (PBLK2), part2 @ 4096
// (OBLK*4), obj list (uint) @ 8192
constexpr int WS_PART1 = 64;
constexpr int WS_PART2 = 4096;
constexpr int WS_LIST  = 8192;
}

__global__ void k_zero(unsigned* counter) { *counter = 0u; }

// ---- clean probe: dense float4 grid-stride read of pred, conf^2 by position.
// 8 VGPR, no LDS traffic in loop, no atomics, no barriers in loop.
__global__ __launch_bounds__(256) void k_pred(const float4* __restrict__ p4,
                                              int np, float* __restrict__ part1)
{
    const int NT = PBLK2 * 256;
    const int np4 = np >> 2;
    int i = blockIdx.x * 256 + threadIdx.x;
    int r = (4 * i) % 30;               // float-pos of q.x mod 30
    const int step = (4 * NT) % 30;
    float acc = 0.f;
    for (; i < np4; i += NT) {
        const float4 q = p4[i];
        acc += ((r == 4) | (r == 9)) ? q.x * q.x : 0.f;
        acc += ((r == 3) | (r == 8)) ? q.y * q.y : 0.f;
        acc += ((r == 2) | (r == 7)) ? q.z * q.z : 0.f;
        acc += ((r == 1) | (r == 6)) ? q.w * q.w : 0.f;
        r += step; if (r >= 30) r -= 30;
    }
    if (blockIdx.x == 0 && threadIdx.x == 0) {       // scalar tail (empty here)
        const float* pf = (const float*)p4;
        for (int f = np4 * 4; f < np; ++f) {
            const int pos = f % 30;
            if (pos == 4 || pos == 9) acc += pf[f] * pf[f];
        }
    }
    #pragma unroll
    for (int off = 32; off >= 1; off >>= 1) acc += __shfl_down(acc, off, 64);
    __shared__ float red[4];
    if ((threadIdx.x & 63) == 0) red[threadIdx.x >> 6] = acc;
    __syncthreads();
    if (threadIdx.x == 0) part1[blockIdx.x] = red[0] + red[1] + red[2] + red[3];
}

// ---- tgt stream: find obj cells (pos%25==4, val>0), per-block LDS compaction,
// ONE global atomic per block (vs 36K same-address atomics in round 5).
__global__ __launch_bounds__(256) void k_tscan(const float4* __restrict__ t4,
                                               int nt,
                                               unsigned* __restrict__ list,
                                               unsigned* __restrict__ counter)
{
    __shared__ unsigned lbuf[TCAP];
    __shared__ unsigned lcnt, lbase;
    if (threadIdx.x == 0) lcnt = 0u;
    __syncthreads();

    const int NT = TBLK2 * 256;
    const int nt4 = nt >> 2;
    int i = blockIdx.x * 256 + threadIdx.x;
    int r = (4 * i) % 25;               // float-pos of q.x mod 25
    const int step = (4 * NT) % 25;
    for (; i < nt4; i += NT) {
        const float4 q = t4[i];
        if (r >= 1 && r <= 4) {         // element (4-r) has pos % 25 == 4
            const int e = 4 - r;
            const float val = (e == 0) ? q.x : (e == 1) ? q.y
                             : (e == 2) ? q.z : q.w;
            if (val > 0.f) {
                const unsigned cell = (unsigned)(4 * i + e - 4) / 25u;
                const unsigned s = atomicAdd(&lcnt, 1u);
                if (s < (unsigned)TCAP) lbuf[s] = cell;
                else { const unsigned g = atomicAdd(counter, 1u); list[g] = cell; }
            }
        }
        r += step; if (r >= 25) r -= 25;
    }
    if (blockIdx.x == 0 && threadIdx.x == 0) {       // scalar tail (empty here)
        const float* tf = (const float*)t4;
        for (int f = nt4 * 4; f < nt; ++f)
            if (f % 25 == 4 && tf[f] > 0.f) {
                const unsigned g = atomicAdd(counter, 1u);
                list[g] = (unsigned)(f - 4) / 25u;
            }
    }
    __syncthreads();
    if (threadIdx.x == 0) {
        const unsigned n = lcnt < (unsigned)TCAP ? lcnt : (unsigned)TCAP;
        lbase = atomicAdd(counter, n);
    }
    __syncthreads();
    const unsigned n = lcnt < (unsigned)TCAP ? lcnt : (unsigned)TCAP;
    for (unsigned s = threadIdx.x; s < n; s += 256) list[lbase + s] = lbuf[s];
}

// ---- obj pass: gather ~6% cells, full loss terms ----
__global__ __launch_bounds__(256) void k_obj(const float* __restrict__ pred,
                                             const float* __restrict__ tgt,
                                             const unsigned* __restrict__ list,
                                             const unsigned* __restrict__ counter,
                                             float* __restrict__ part2)
{
    const unsigned count = *counter;
    float v0 = 0.f, v1 = 0.f, v2 = 0.f, v3 = 0.f;   // v2 = -rconf^2 correction

    for (unsigned idx = blockIdx.x * 256 + threadIdx.x; idx < count;
         idx += OBLK * 256) {
        const unsigned cell = list[idx];
        const float* p = pred + (size_t)cell * PF;
        const float* t = tgt + (size_t)cell * TF;

        const int j = (int)(cell % S);
        const int i = (int)((cell / S) % S);
        const float invS = 1.0f / (float)S;

        const float2 p01 = *(const float2*)(p + 0);
        const float2 p23 = *(const float2*)(p + 2);
        const float2 p45 = *(const float2*)(p + 4);
        const float2 p67 = *(const float2*)(p + 6);
        const float2 p89 = *(const float2*)(p + 8);
        const float gx = t[0], gy = t[1], gw = t[2], gh = t[3];

        const float gcx = ((float)j + gx) * invS;
        const float gcy = ((float)i + gy) * invS;
        const float gx1 = gcx - gw * 0.5f, gy1 = gcy - gh * 0.5f;
        const float gx2 = gcx + gw * 0.5f, gy2 = gcy + gh * 0.5f;
        const float garea = (gx2 - gx1) * (gy2 - gy1);

        const float bx[B]  = {p01.x, p45.y};
        const float by[B]  = {p01.y, p67.x};
        const float bw_[B] = {p23.x, p67.y};
        const float bh[B]  = {p23.y, p89.x};
        const float cf[B]  = {p45.x, p89.y};
        float iou[B];
        #pragma unroll
        for (int b = 0; b < B; ++b) {
            const float cx = ((float)j + bx[b]) * invS;
            const float cy = ((float)i + by[b]) * invS;
            const float x1 = cx - bw_[b] * 0.5f, y1 = cy - bh[b] * 0.5f;
            const float x2 = cx + bw_[b] * 0.5f, y2 = cy + bh[b] * 0.5f;
            const float ix1 = fmaxf(x1, gx1), iy1 = fmaxf(y1, gy1);
            const float ix2 = fminf(x2, gx2), iy2 = fminf(y2, gy2);
            const float inter = fmaxf(ix2 - ix1, 0.f) * fmaxf(iy2 - iy1, 0.f);
            const float parea = (x2 - x1) * (y2 - y1);
            iou[b] = inter / (parea + garea - inter + EPS);
        }
        const int best = (iou[1] > iou[0]) ? 1 : 0;
        const float rconf = cf[best], riou = iou[best];

        const float dx = bx[best] - gx, dy = by[best] - gy;
        const float swd = sqrtf(bw_[best] + EPS) - sqrtf(gw + EPS);
        const float shd = sqrtf(bh[best] + EPS) - sqrtf(gh + EPS);
        v0 += dx * dx + dy * dy + swd * swd + shd * shd;
        const float dc = rconf - riou;
        v1 += dc * dc;
        v2 -= rconf * rconf;

        float se = 0.f, dot = 0.f, sg = 0.f;
        #pragma unroll
        for (int c = 0; c < C; c += 2) {
            const float2 lc = *(const float2*)(p + 10 + c);
            const float g0 = t[5 + c], g1 = t[6 + c];
            se  += __expf(lc.x) + __expf(lc.y);
            dot += g0 * lc.x + g1 * lc.y;
            sg  += g0 + g1;
        }
        v3 += __logf(se) * sg - dot;
    }

    float v[4] = {v0, v1, v2, v3};
    #pragma unroll
    for (int off = 32; off >= 1; off >>= 1) {
        v[0] += __shfl_down(v[0], off, 64);
        v[1] += __shfl_down(v[1], off, 64);
        v[2] += __shfl_down(v[2], off, 64);
        v[3] += __shfl_down(v[3], off, 64);
    }
    __shared__ float red[16];
    const int lane = threadIdx.x & 63;
    const int wave = threadIdx.x >> 6;
    if (lane == 0) {
        red[wave * 4 + 0] = v[0];
        red[wave * 4 + 1] = v[1];
        red[wave * 4 + 2] = v[2];
        red[wave * 4 + 3] = v[3];
    }
    __syncthreads();
    if (threadIdx.x < 4)
        part2[blockIdx.x * 4 + threadIdx.x] =
            red[threadIdx.x] + red[4 + threadIdx.x] +
            red[8 + threadIdx.x] + red[12 + threadIdx.x];
}

// ---- final reduce ----
__global__ __launch_bounds__(256) void k_fin2(const float* __restrict__ part1,
                                              const float* __restrict__ part2,
                                              float* __restrict__ out, float n)
{
    const int tid = threadIdx.x;
    float a0 = 0.f, a1 = 0.f, a2 = 0.f, a3 = 0.f;
    for (int r = tid; r < PBLK2; r += 256) a2 += part1[r];     // noobj base
    for (int r = tid; r < OBLK; r += 256) {
        const float4 q = *(const float4*)(part2 + r * 4);
        a0 += q.x; a1 += q.y; a2 += q.z; a3 += q.w;
    }
    float v[4] = {a0, a1, a2, a3};
    #pragma unroll
    for (int off = 32; off >= 1; off >>= 1) {
        v[0] += __shfl_down(v[0], off, 64);
        v[1] += __shfl_down(v[1], off, 64);
        v[2] += __shfl_down(v[2], off, 64);
        v[3] += __shfl_down(v[3], off, 64);
    }
    __shared__ float red[16];
    const int lane = tid & 63;
    const int wave = tid >> 6;
    if (lane == 0) {
        red[wave * 4 + 0] = v[0];
        red[wave * 4 + 1] = v[1];
        red[wave * 4 + 2] = v[2];
        red[wave * 4 + 3] = v[3];
    }
    __syncthreads();
    if (tid == 0) {
        const float coord  = red[0] + red[4] + red[8]  + red[12];
        const float cobj   = red[1] + red[5] + red[9]  + red[13];
        const float cnoobj = red[2] + red[6] + red[10] + red[14];
        const float ccls   = red[3] + red[7] + red[11] + red[15];
        const float inv = 1.0f / n;
        out[0] = coord * inv;
        out[1] = cobj * inv;
        out[2] = cnoobj * inv;
        out[3] = ccls * inv;
        out[4] = (LAMBDA_COORD * coord + cobj + LAMBDA_NOOBJ * cnoobj + ccls) * inv;
    }
}

// ---- fallback (round-1 staged kernel) if ws too small ----
__global__ __launch_bounds__(256) void k_main_fb(const float* __restrict__ pred,
                                                 const float* __restrict__ tgt,
                                                 float* __restrict__ part,
                                                 int n_cells) {
    __shared__ float lp[256 * PF];
    __shared__ float lt[256 * TF];
    const int tid = threadIdx.x;
    const int block0 = blockIdx.x * 256;
    const int cells = min(256, n_cells - block0);
    const size_t pbase = (size_t)block0 * PF;
    const size_t tbase = (size_t)block0 * TF;
    for (int o = tid; o < cells * PF; o += 256) lp[o] = pred[pbase + o];
    for (int o = tid; o < cells * TF; o += 256) lt[o] = tgt[tbase + o];
    __syncthreads();

    float v0 = 0.f, v1 = 0.f, v2 = 0.f, v3 = 0.f;
    if (tid < cells) {
        const int cell = block0 + tid;
        const float* p = lp + tid * PF;
        const float* t = lt + tid * TF;
        const float c0 = p[4], c1 = p[9];
        v2 = c0 * c0 + c1 * c1;
        if (t[4] > 0.f) {
            const int j = cell % S;
            const int i = (cell / S) % S;
            const float invS = 1.0f / (float)S;
            const float gx = t[0], gy = t[1], gw = t[2], gh = t[3];
            const float gcx = ((float)j + gx) * invS;
            const float gcy = ((float)i + gy) * invS;
            const float gx1 = gcx - gw * 0.5f, gy1 = gcy - gh * 0.5f;
            const float gx2 = gcx + gw * 0.5f, gy2 = gcy + gh * 0.5f;
            const float garea = (gx2 - gx1) * (gy2 - gy1);
            const float bx[B]  = {p[0], p[5]};
            const float by[B]  = {p[1], p[6]};
            const float bw_[B] = {p[2], p[7]};
            const float bh[B]  = {p[3], p[8]};
            const float cf[B]  = {c0, c1};
            float iou[B];
            #pragma unroll
            for (int b = 0; b < B; ++b) {
                const float cx = ((float)j + bx[b]) * invS;
                const float cy = ((float)i + by[b]) * invS;
                const float x1 = cx - bw_[b] * 0.5f, y1 = cy - bh[b] * 0.5f;
                const float x2 = cx + bw_[b] * 0.5f, y2 = cy + bh[b] * 0.5f;
                const float ix1 = fmaxf(x1, gx1), iy1 = fmaxf(y1, gy1);
                const float ix2 = fminf(x2, gx2), iy2 = fminf(y2, gy2);
                const float inter = fmaxf(ix2 - ix1, 0.f) * fmaxf(iy2 - iy1, 0.f);
                const float parea = (x2 - x1) * (y2 - y1);
                iou[b] = inter / (parea + garea - inter + EPS);
            }
            const int best = (iou[1] > iou[0]) ? 1 : 0;
            const float rconf = cf[best], riou = iou[best];
            const float dx = bx[best] - gx, dy = by[best] - gy;
            const float swd = sqrtf(bw_[best] + EPS) - sqrtf(gw + EPS);
            const float shd = sqrtf(bh[best] + EPS) - sqrtf(gh + EPS);
            v0 = dx*dx + dy*dy + swd*swd + shd*shd;
            const float dc = rconf - riou;
            v1 = dc * dc;
            v2 -= rconf * rconf;
            float se = 0.f, dot = 0.f, sg = 0.f;
            #pragma unroll
            for (int c = 0; c < C; c += 2) {
                const float2 lc = *(const float2*)(p + 10 + c);
                const float g0 = t[5 + c], g1 = t[6 + c];
                se  += __expf(lc.x) + __expf(lc.y);
                dot += g0 * lc.x + g1 * lc.y;
                sg  += g0 + g1;
            }
            v3 = __logf(se) * sg - dot;
        }
    }
    float v[4] = {v0, v1, v2, v3};
    #pragma unroll
    for (int off = 32; off >= 1; off >>= 1) {
        v[0] += __shfl_down(v[0], off, 64);
        v[1] += __shfl_down(v[1], off, 64);
        v[2] += __shfl_down(v[2], off, 64);
        v[3] += __shfl_down(v[3], off, 64);
    }
    __shared__ float red[16];
    const int lane = tid & 63;
    const int wave = tid >> 6;
    if (lane == 0) {
        red[wave*4+0] = v[0]; red[wave*4+1] = v[1];
        red[wave*4+2] = v[2]; red[wave*4+3] = v[3];
    }
    __syncthreads();
    if (tid < 4)
        part[blockIdx.x * 4 + tid] =
            red[tid] + red[4+tid] + red[8+tid] + red[12+tid];
}

__global__ __launch_bounds__(256) void k_fin_fb(const float* __restrict__ part,
                                                float* __restrict__ out,
                                                int nblk, float n) {
    const int tid = threadIdx.x;
    float a0 = 0.f, a1 = 0.f, a2 = 0.f, a3 = 0.f;
    for (int r = tid; r < nblk; r += 256) {
        const float4 q = *(const float4*)(part + r * 4);
        a0 += q.x; a1 += q.y; a2 += q.z; a3 += q.w;
    }
    float v[4] = {a0, a1, a2, a3};
    #pragma unroll
    for (int off = 32; off >= 1; off >>= 1) {
        v[0] += __shfl_down(v[0], off, 64);
        v[1] += __shfl_down(v[1], off, 64);
        v[2] += __shfl_down(v[2], off, 64);
        v[3] += __shfl_down(v[3], off, 64);
    }
    __shared__ float red[16];
    const int lane = tid & 63;
    const int wave = tid >> 6;
    if (lane == 0) {
        red[wave*4+0] = v[0]; red[wave*4+1] = v[1];
        red[wave*4+2] = v[2]; red[wave*4+3] = v[3];
    }
    __syncthreads();
    if (tid == 0) {
        const float coord  = red[0] + red[4] + red[8]  + red[12];
        const float cobj   = red[1] + red[5] + red[9]  + red[13];
        const float cnoobj = red[2] + red[6] + red[10] + red[14];
        const float ccls   = red[3] + red[7] + red[11] + red[15];
        const float inv = 1.0f / n;
        out[0] = coord * inv;
        out[1] = cobj * inv;
        out[2] = cnoobj * inv;
        out[3] = ccls * inv;
        out[4] = (LAMBDA_COORD * coord + cobj + LAMBDA_NOOBJ * cnoobj + ccls) * inv;
    }
}

extern "C" void kernel_launch(void* const* d_in, const int* in_sizes, int n_in,
                              void* d_out, int out_size, void* d_ws, size_t ws_size,
                              hipStream_t stream) {
    const float* pred = (const float*)d_in[0];
    const float* tgt  = (const float*)d_in[1];
    float* out = (float*)d_out;
    float* wsf = (float*)d_ws;

    const int n_cells = in_sizes[0] / PF;          // 802816
    const float bs = (float)(n_cells / (S * S));   // 16384

    const size_t need = ((size_t)WS_LIST + (size_t)n_cells) * 4;
    if (ws_size >= need) {
        unsigned* counter = (unsigned*)d_ws;
        float* part1 = wsf + WS_PART1;
        float* part2 = wsf + WS_PART2;
        unsigned* list = (unsigned*)(wsf + WS_LIST);

        k_zero<<<1, 1, 0, stream>>>(counter);
        k_pred<<<PBLK2, 256, 0, stream>>>((const float4*)pred,
                                          n_cells * PF, part1);
        k_tscan<<<TBLK2, 256, 0, stream>>>((const float4*)tgt,
                                           n_cells * TF, list, counter);
        k_obj<<<OBLK, 256, 0, stream>>>(pred, tgt, list, counter, part2);
        k_fin2<<<1, 256, 0, stream>>>(part1, part2, out, bs);
    } else {
        float* part = wsf;
        const int nblk = (n_cells + 255) / 256;
        k_main_fb<<<nblk, 256, 0, stream>>>(pred, tgt, part, n_cells);
        k_fin_fb<<<1, 256, 0, stream>>>(part, out, nblk, bs);
    }
}

// Round 7
// 197.868 us; speedup vs baseline: 2.8935x; 1.0694x over previous
//
#include <hip/hip_runtime.h>
#include <math.h>

namespace {
constexpr int S = 7;
constexpr int B = 2;
constexpr int C = 20;
constexpr int PF = B * 5 + C;   // 30 floats per cell (predictions)
constexpr int TF = 5 + C;       // 25 floats per cell (targets)
constexpr float EPS = 1e-6f;
constexpr float LAMBDA_COORD = 5.0f;
constexpr float LAMBDA_NOOBJ = 0.5f;
constexpr int BLK = 256;
constexpr int CH = 256;                  // cells per block (== BLK)
constexpr int PRED_FLOATS = CH * PF;     // 7680 floats = 30720 B
constexpr int TGT_FLOATS  = CH * TF;     // 6400 floats = 25600 B
}

#define GLOBAL_AS __attribute__((address_space(1)))
#define LDS_AS    __attribute__((address_space(3)))

// Session-best structure (round 1, 198.1 us headline, k_main 66 us = at the
// measured ~2.6 TB/s read-service ceiling for this 176.6 MB mixed L3/HBM
// footprint). Stage each block's 256 cells into LDS via coalesced async
// global_load_lds (16B/lane), then compute from LDS.
__global__ __launch_bounds__(BLK) void k_main(const float* __restrict__ pred,
                                              const float* __restrict__ tgt,
                                              float* __restrict__ part,
                                              int n_cells) {
    __shared__ float lp[PRED_FLOATS];
    __shared__ float lt[TGT_FLOATS];

    const int tid = threadIdx.x;
    const int block0 = blockIdx.x * CH;
    const int remc = n_cells - block0;
    const int cells = remc < CH ? remc : CH;

    const size_t pbase = (size_t)block0 * PF;
    const size_t tbase = (size_t)block0 * TF;

    if (cells == CH) {
        // Fast path: full chunk, async direct-to-LDS, 16B per lane per call.
        #pragma unroll
        for (int o = 0; o < PRED_FLOATS; o += BLK * 4) {
            const int idx = o + tid * 4;
            if (idx < PRED_FLOATS) {
                __builtin_amdgcn_global_load_lds(
                    (const GLOBAL_AS void*)(pred + pbase + idx),
                    (LDS_AS void*)(lp + idx), 16, 0, 0);
            }
        }
        #pragma unroll
        for (int o = 0; o < TGT_FLOATS; o += BLK * 4) {
            const int idx = o + tid * 4;
            if (idx < TGT_FLOATS) {
                __builtin_amdgcn_global_load_lds(
                    (const GLOBAL_AS void*)(tgt + tbase + idx),
                    (LDS_AS void*)(lt + idx), 16, 0, 0);
            }
        }
        asm volatile("s_waitcnt vmcnt(0)" ::: "memory");
    } else {
        // Cold path: partial tail chunk (unused for the bench shape).
        for (int o = tid; o < cells * PF; o += BLK) lp[o] = pred[pbase + o];
        for (int o = tid; o < cells * TF; o += BLK) lt[o] = tgt[tbase + o];
    }
    __syncthreads();

    float v0 = 0.f, v1 = 0.f, v2 = 0.f, v3 = 0.f;
    if (tid < cells) {
        const int cell = block0 + tid;
        const float* p = lp + tid * PF;   // LDS, stride 30: 2-way bank alias (free)
        const float* t = lt + tid * TF;   // LDS, stride 25: conflict-free

        const float c0 = p[4], c1 = p[9];
        const float t4 = t[4];

        v2 = c0 * c0 + c1 * c1;                       // noobj base term

        if (t4 > 0.f) {                               // ~6% of lanes
            const int j = cell % S;
            const int i = (cell / S) % S;
            const float invS = 1.0f / (float)S;

            const float2 p01 = *(const float2*)(p + 0);   // (x0, y0)
            const float2 p23 = *(const float2*)(p + 2);   // (w0, h0)
            const float2 p67 = *(const float2*)(p + 6);   // (y1, w1)
            const float gx = t[0], gy = t[1], gw = t[2], gh = t[3];

            const float gcx = ((float)j + gx) * invS;
            const float gcy = ((float)i + gy) * invS;
            const float gx1 = gcx - gw * 0.5f, gy1 = gcy - gh * 0.5f;
            const float gx2 = gcx + gw * 0.5f, gy2 = gcy + gh * 0.5f;
            const float garea = (gx2 - gx1) * (gy2 - gy1);

            const float bx[B]  = {p01.x, p[5]};
            const float by[B]  = {p01.y, p67.x};
            const float bw_[B] = {p23.x, p67.y};
            const float bh[B]  = {p23.y, p[8]};
            const float cf[B]  = {c0, c1};
            float iou[B];
            #pragma unroll
            for (int b = 0; b < B; ++b) {
                const float cx = ((float)j + bx[b]) * invS;
                const float cy = ((float)i + by[b]) * invS;
                const float x1 = cx - bw_[b] * 0.5f, y1 = cy - bh[b] * 0.5f;
                const float x2 = cx + bw_[b] * 0.5f, y2 = cy + bh[b] * 0.5f;
                const float ix1 = fmaxf(x1, gx1), iy1 = fmaxf(y1, gy1);
                const float ix2 = fminf(x2, gx2), iy2 = fminf(y2, gy2);
                const float inter = fmaxf(ix2 - ix1, 0.f) * fmaxf(iy2 - iy1, 0.f);
                const float parea = (x2 - x1) * (y2 - y1);
                iou[b] = inter / (parea + garea - inter + EPS);
            }
            const int best = (iou[1] > iou[0]) ? 1 : 0;   // first max wins
            const float rconf = cf[best], riou = iou[best];

            const float dx = bx[best] - gx, dy = by[best] - gy;
            const float swd = sqrtf(bw_[best] + EPS) - sqrtf(gw + EPS);
            const float shd = sqrtf(bh[best] + EPS) - sqrtf(gh + EPS);
            v0 = dx*dx + dy*dy + swd*swd + shd*shd;       // coord
            const float dc = rconf - riou;
            v1 = dc * dc;                                  // conf_obj
            v2 -= rconf * rconf;                           // responsible box excluded

            // class: lse*sum(g) - dot(g,l). Logits in [0,1) -> no max pass needed.
            float se = 0.f, dot = 0.f, sg = 0.f;
            #pragma unroll
            for (int c = 0; c < C; c += 2) {
                const float2 lc = *(const float2*)(p + 10 + c);
                const float g0 = t[5 + c], g1 = t[6 + c];
                se  += __expf(lc.x) + __expf(lc.y);
                dot += g0 * lc.x + g1 * lc.y;
                sg  += g0 + g1;
            }
            v3 = __logf(se) * sg - dot;                    // class
        }
    }

    // ---- reduce: wave64 butterfly -> LDS -> per-block partial slot ----
    float v[4] = {v0, v1, v2, v3};
    #pragma unroll
    for (int off = 32; off >= 1; off >>= 1) {
        v[0] += __shfl_down(v[0], off, 64);
        v[1] += __shfl_down(v[1], off, 64);
        v[2] += __shfl_down(v[2], off, 64);
        v[3] += __shfl_down(v[3], off, 64);
    }
    __shared__ float red[16];   // 4 waves x 4 sums
    const int lane = tid & 63;
    const int wave = tid >> 6;
    if (lane == 0) {
        red[wave * 4 + 0] = v[0];
        red[wave * 4 + 1] = v[1];
        red[wave * 4 + 2] = v[2];
        red[wave * 4 + 3] = v[3];
    }
    __syncthreads();
    if (tid < 4)
        part[blockIdx.x * 4 + tid] =
            red[tid] + red[4 + tid] + red[8 + tid] + red[12 + tid];
}

// Single block: reduce nblk x 4 partials, write 5 outputs.
__global__ __launch_bounds__(BLK) void k_fin(const float* __restrict__ part,
                                             float* __restrict__ out,
                                             int nblk, float n) {
    const int tid = threadIdx.x;
    float a0 = 0.f, a1 = 0.f, a2 = 0.f, a3 = 0.f;
    for (int r = tid; r < nblk; r += BLK) {
        const float4 q = *(const float4*)(part + r * 4);
        a0 += q.x; a1 += q.y; a2 += q.z; a3 += q.w;
    }
    float v[4] = {a0, a1, a2, a3};
    #pragma unroll
    for (int off = 32; off >= 1; off >>= 1) {
        v[0] += __shfl_down(v[0], off, 64);
        v[1] += __shfl_down(v[1], off, 64);
        v[2] += __shfl_down(v[2], off, 64);
        v[3] += __shfl_down(v[3], off, 64);
    }
    __shared__ float red[16];
    const int lane = tid & 63;
    const int wave = tid >> 6;
    if (lane == 0) {
        red[wave * 4 + 0] = v[0];
        red[wave * 4 + 1] = v[1];
        red[wave * 4 + 2] = v[2];
        red[wave * 4 + 3] = v[3];
    }
    __syncthreads();
    if (tid == 0) {
        const float coord  = red[0] + red[4] + red[8] + red[12];
        const float cobj   = red[1] + red[5] + red[9] + red[13];
        const float cnoobj = red[2] + red[6] + red[10] + red[14];
        const float ccls   = red[3] + red[7] + red[11] + red[15];
        const float inv = 1.0f / n;
        out[0] = coord * inv;
        out[1] = cobj * inv;
        out[2] = cnoobj * inv;
        out[3] = ccls * inv;
        out[4] = (LAMBDA_COORD * coord + cobj + LAMBDA_NOOBJ * cnoobj + ccls) * inv;
    }
}

extern "C" void kernel_launch(void* const* d_in, const int* in_sizes, int n_in,
                              void* d_out, int out_size, void* d_ws, size_t ws_size,
                              hipStream_t stream) {
    const float* pred = (const float*)d_in[0];
    const float* tgt  = (const float*)d_in[1];
    float* out  = (float*)d_out;
    float* part = (float*)d_ws;

    const int n_cells = in_sizes[0] / PF;          // 802816
    const float bs = (float)(n_cells / (S * S));   // 16384
    const int nblk = (n_cells + BLK - 1) / BLK;    // 3136

    k_main<<<nblk, BLK, 0, stream>>>(pred, tgt, part, n_cells);
    k_fin<<<1, BLK, 0, stream>>>(part, out, nblk, bs);
}